// Round 23
// baseline (80.327 us; speedup 1.0000x reference)
//
#include <hip/hip_runtime.h>

typedef unsigned long long u64;
typedef unsigned int u32;
typedef unsigned short u16;

#define N1 4096
#define N2 2048
#define NT 6144
#define CAP 4096
#define MCAP 4096
#define IMG 1280.0f
#define MATCH_IOU_T 0.8f
#define NMS_IOU_T 0.95f
#define NRANKBLK (NT / 16)
#define STH 1024
#define NBX 16            // x1 bins per label
#define BINW_INV (1.0f/80.0f)   // raw-pixel bin width 80 = 1280/16
#define NBSCALE 16.0f     // normalized x1 * 16 -> bin

// IoU with exact op-order mirroring of the reference (no FMA contraction).
__device__ __forceinline__ float iou_f(const float* a, const float* b) {
    float x1 = fmaxf(a[0], b[0]);
    float y1 = fmaxf(a[1], b[1]);
    float x2 = fminf(a[2], b[2]);
    float y2 = fminf(a[3], b[3]);
    float dx = fmaxf(__fsub_rn(x2, x1), 0.0f);
    float dy = fmaxf(__fsub_rn(y2, y1), 0.0f);
    float inter = __fmul_rn(dx, dy);
    float a1 = __fmul_rn(__fsub_rn(a[2], a[0]), __fsub_rn(a[3], a[1]));
    float a2 = __fmul_rn(__fsub_rn(b[2], b[0]), __fsub_rn(b[3], b[1]));
    float den = __fsub_rn(__fadd_rn(a1, a2), inter);
    return __fdiv_rn(inter, den);
}

__device__ __forceinline__ u64 make_key(float f, int idx) {
    u32 u = __float_as_uint(f);
    u32 asc = (u >> 31) ? ~u : (u | 0x80000000u);
    return (((u64)(~asc)) << 32) | (u32)idx;
}

__device__ __forceinline__ u64 row_key(const float* sall, const unsigned char* used_g,
                                       int idx) {
    float sc = sall[idx];
    int val = (idx < N1) ? 1 : (used_g[idx - N1] ? 0 : 1);
    return make_key(val ? sc : -1.0f, idx);
}

__device__ __forceinline__ int clampb(int b) { return min(max(b, 0), NBX - 1); }

// k0: zero counters; bin frcnn boxes into (label x 16 x1-bin) CSR (raw px);
// compute max frcnn width (conservative window margin). Exclusion by bin
// window only removes pairs with PROVABLY zero x-overlap (IoU=0 < thresh).
// List order within a bin is timing-dependent but membership-only (k2 sorts).
__global__ void __launch_bounds__(STH) k0(const int* fl, const float* fb,
                                          int* cnt, u16* flst, int* foff,
                                          float* wmaxf_g) {
    __shared__ int fc[2 * NBX];
    __shared__ int fo[2 * NBX + 1];
    __shared__ float wmx[STH / 64];
    int tid = threadIdx.x;
    if (tid == 0) { cnt[0] = 0; cnt[1] = 0; }
    if (tid < 2 * NBX) fc[tid] = 0;
    __syncthreads();
    float w = 0.0f;
    for (int j = tid; j < N2; j += STH) {
        float x1 = fb[j * 4], x2 = fb[j * 4 + 2];
        w = fmaxf(w, __fsub_rn(x2, x1));
        atomicAdd(&fc[fl[j] * NBX + clampb((int)(x1 * BINW_INV))], 1);
    }
#pragma unroll
    for (int s = 32; s > 0; s >>= 1) w = fmaxf(w, __shfl_down(w, s, 64));
    if ((tid & 63) == 0) wmx[tid >> 6] = w;
    __syncthreads();
    if (tid == 0) {
        float mw = wmx[0];
        for (int q = 1; q < STH / 64; q++) mw = fmaxf(mw, wmx[q]);
        *wmaxf_g = mw + 1.0f;   // +1px slack: absorbs width-rounding, stays conservative
        int acc = 0;
        for (int b = 0; b < 2 * NBX; b++) { fo[b] = acc; acc += fc[b]; }
        fo[2 * NBX] = acc;
    }
    __syncthreads();
    if (tid < 2 * NBX) fc[tid] = fo[tid];     // reuse as fill cursors
    if (tid < 2 * NBX + 1) foff[tid] = fo[tid];
    __syncthreads();
    for (int j = tid; j < N2; j += STH) {
        float x1 = fb[j * 4];
        int p = atomicAdd(&fc[fl[j] * NBX + clampb((int)(x1 * BINW_INV))], 1);
        flst[p] = (u16)j;
    }
}

// kX: blocks [0,N1): one yolo row — scan only same-label frcnn entries whose
// x1-bin can possibly overlap (contiguous CSR range); emit candidate pairs.
// Blocks [N1,N1+8): frcnn rows' defaults.
__global__ void __launch_bounds__(256) kX(const float* yb, const float* ys,
                                          const int* yl, const float* fb,
                                          const float* fs,
                                          const u16* flst, const int* foff,
                                          const float* wmaxf,
                                          int* mpcount, u64* mpk, float* mpi,
                                          float* sball, float* sall) {
    int tid = threadIdx.x;
    if (blockIdx.x < N1) {
        int i = blockIdx.x;
        float ax1 = yb[i * 4], ax2 = yb[i * 4 + 2];
        float a[4];
#pragma unroll
        for (int c = 0; c < 4; c++) a[c] = __fdiv_rn(yb[i * 4 + c], IMG);
        int lab = yl[i];
        float wm = *wmaxf;
        int blo = clampb((int)((ax1 - wm) * BINW_INV));
        int bhi = clampb((int)(ax2 * BINW_INV));
        int t0 = foff[lab * NBX + blo];
        int t1 = foff[lab * NBX + bhi + 1];
        for (int t = t0 + tid; t < t1; t += 256) {
            int j = flst[t];
            float bb[4];
#pragma unroll
            for (int c = 0; c < 4; c++) bb[c] = __fdiv_rn(fb[j * 4 + c], IMG);
            float v = iou_f(a, bb);
            if (v >= MATCH_IOU_T) {
                int pos = atomicAdd(mpcount, 1);
                if (pos < MCAP) { mpk[pos] = (((u64)(u32)i) << 32) | (u32)j; mpi[pos] = v; }
            }
        }
        if (tid == 0) {
#pragma unroll
            for (int c = 0; c < 4; c++) sball[i * 4 + c] = a[c];
            sall[i] = __fmul_rn(ys[i], 0.5f);
        }
    } else {
        int j = (blockIdx.x - N1) * 256 + tid;   // 0..2047
#pragma unroll
        for (int c = 0; c < 4; c++) sball[(N1 + j) * 4 + c] = __fdiv_rn(fb[j * 4 + c], IMG);
        sall[N1 + j] = __fmul_rn(fs[j], 0.5f);
    }
}

// k2: single block, 1024 threads. Sort pairs (init capped to pow2(np)),
// thread-0 greedy walk, merged-row patches + used[]; then build the
// FINAL-box (label x bin) CSR + max-width for the NMS phase.
__global__ void __launch_bounds__(STH) k2(const float* fb, const float* fs,
                                          const int* yl, const int* fl,
                                          const int* mpcount, const u64* mpk,
                                          const float* mpi,
                                          float* sball, float* sall,
                                          unsigned char* used_g,
                                          u16* rlst, int* roff, float* wmaxa_g) {
    __shared__ u64 pk[MCAP];            // 32 KB
    __shared__ float pv[MCAP];          // 16 KB
    __shared__ unsigned char dec[MCAP]; //  4 KB
    __shared__ unsigned char used[N2];  //  2 KB
    __shared__ int rc2[2 * NBX];
    __shared__ int ro[2 * NBX + 1];
    __shared__ float wmx[STH / 64];
    int tid = threadIdx.x;
    int np = *mpcount;
    if (np > MCAP) np = MCAP;
    int m = 2;
    while (m < np) m <<= 1;   // uniform
    for (int t = tid; t < m; t += STH) {
        pk[t] = (t < np) ? mpk[t] : ~0ULL;
        pv[t] = (t < np) ? mpi[t] : 0.0f;
    }
    for (int t = tid; t < np; t += STH) dec[t] = 0;
    for (int j = tid; j < N2; j += STH) used[j] = 0;
    __syncthreads();
    if (np > 0) {
        for (int k2v = 2; k2v <= m; k2v <<= 1) {
            for (int jj = k2v >> 1; jj > 0; jj >>= 1) {
                for (int idx = tid; idx < m; idx += STH) {
                    int l = idx ^ jj;
                    if (l > idx) {
                        u64 A = pk[idx], B = pk[l];
                        bool up = ((idx & k2v) == 0);
                        if (up ? (A > B) : (A < B)) {
                            pk[idx] = B; pk[l] = A;
                            float fA = pv[idx]; pv[idx] = pv[l]; pv[l] = fA;
                        }
                    }
                }
                __syncthreads();
            }
        }
        if (tid == 0) {
            int cur_i = -1, best_p = -1, best_j = -1;
            float best_v = -1.0f;
            for (int p = 0; p < np; p++) {
                u64 pr = pk[p];
                int i = (int)(pr >> 32);
                int j = (int)(pr & 0xffffffffu);
                if (i != cur_i) {
                    if (best_p >= 0) { dec[best_p] = 1; used[best_j] = 1; }
                    cur_i = i; best_p = -1; best_j = -1; best_v = -1.0f;
                }
                if (!used[j]) {
                    float v = pv[p];
                    if (v > best_v) { best_v = v; best_p = p; best_j = j; }
                }
            }
            if (best_p >= 0) { dec[best_p] = 1; used[best_j] = 1; }
        }
        __syncthreads();
        for (int p = tid; p < np; p += STH) {
            if (dec[p]) {
                u64 pr = pk[p];
                int i = (int)(pr >> 32);
                int j = (int)(pr & 0xffffffffu);
                float s2 = __fmul_rn(fs[j], 0.5f);
                float sc0 = sall[i];
                float tot = __fadd_rn(sc0, s2);
#pragma unroll
                for (int cc = 0; cc < 4; cc++) {
                    float b2v = __fdiv_rn(fb[j * 4 + cc], IMG);
                    float merged = __fdiv_rn(
                        __fadd_rn(__fmul_rn(sball[i * 4 + cc], sc0),
                                  __fmul_rn(b2v, s2)), tot);
                    sball[i * 4 + cc] = merged;
                }
                sall[i] = tot;
            }
        }
    }
    for (int j = tid; j < N2; j += STH) used_g[j] = used[j];
    __syncthreads();   // merges + used visible block-wide (intra-block global)
    // ---- final-box bin CSR (normalized x1) + max final width ----
    if (tid < 2 * NBX) rc2[tid] = 0;
    __syncthreads();
    float w = 0.0f;
    for (int r = tid; r < NT; r += STH) {
        float x1 = sball[r * 4], x2 = sball[r * 4 + 2];
        w = fmaxf(w, __fsub_rn(x2, x1));
        int lab = (r < N1) ? yl[r] : fl[r - N1];
        atomicAdd(&rc2[lab * NBX + clampb((int)(x1 * NBSCALE))], 1);
    }
#pragma unroll
    for (int s = 32; s > 0; s >>= 1) w = fmaxf(w, __shfl_down(w, s, 64));
    if ((tid & 63) == 0) wmx[tid >> 6] = w;
    __syncthreads();
    if (tid == 0) {
        float mw = wmx[0];
        for (int q = 1; q < STH / 64; q++) mw = fmaxf(mw, wmx[q]);
        *wmaxa_g = mw + 0.00078125f;   // +1px (normalized) conservative slack
        int acc = 0;
        for (int b = 0; b < 2 * NBX; b++) { ro[b] = acc; acc += rc2[b]; }
        ro[2 * NBX] = acc;
    }
    __syncthreads();
    if (tid < 2 * NBX) rc2[tid] = ro[tid];
    if (tid < 2 * NBX + 1) roff[tid] = ro[tid];
    __syncthreads();
    for (int r = tid; r < NT; r += STH) {
        float x1 = sball[r * 4];
        int lab = (r < N1) ? yl[r] : fl[r - N1];
        int p = atomicAdd(&rc2[lab * NBX + clampb((int)(x1 * NBSCALE))], 1);
        rlst[p] = (u16)r;
    }
}

// kYZ: 384 blocks, both roles per block (r22 post-mortem: the 6144 separate
// NMS blocks were drain-overhead-dominated at ~600 compares each).
// Phase 1: rank this block's 16 rows against all 6144 inline keys; gather.
// Phase 2: NMS-pair detect for the SAME 16 rows over their label-bin windows
// (b>a, both valid, IoU >= 0.95) -> atomic append. No barrier needed
// between phases (independent data).
__global__ void __launch_bounds__(256) kYZ(const float* sball, const float* sall,
                                           const unsigned char* used_g,
                                           const int* yl, const int* fl,
                                           const u16* rlst, const int* roff,
                                           const float* wmaxa,
                                           int* ord, float* out,
                                           int* pcount, u64* phi, u64* plo) {
    __shared__ int cnts[16];
    int tid = threadIdx.x;
    if (tid < 16) cnts[tid] = 0;
    __syncthreads();
    int i0 = blockIdx.x * 16;
    u64 myk[16];
#pragma unroll
    for (int g = 0; g < 16; g++) myk[g] = row_key(sall, used_g, i0 + g);
    int local[16];
#pragma unroll
    for (int g = 0; g < 16; g++) local[g] = 0;
    for (int j = tid; j < NT; j += 256) {
        u64 kj = row_key(sall, used_g, j);
#pragma unroll
        for (int g = 0; g < 16; g++) local[g] += (kj < myk[g]) ? 1 : 0;
    }
#pragma unroll
    for (int g = 0; g < 16; g++) {
        int v = local[g];
#pragma unroll
        for (int s = 32; s > 0; s >>= 1) v += __shfl_down(v, s, 64);
        if ((tid & 63) == 0) atomicAdd(&cnts[g], v);
    }
    __syncthreads();
    if (tid < 16) {
        int i = i0 + tid;
        int r = cnts[tid];
        int lab = (i < N1) ? yl[i] : fl[i - N1];
#pragma unroll
        for (int c = 0; c < 4; c++)
            out[r * 4 + c] = __fmul_rn(sball[i * 4 + c], IMG);
        out[24576 + r] = (lab == 0) ? 2.0f : 1.0f;
        out[24576 + NT + r] = sall[i];
        ord[r] = i;
    }
    // ---- Phase 2: NMS-pair detect for rows i0..i0+15 ----
    float wm = *wmaxa;
    for (int g = 0; g < 16; g++) {
        int a = i0 + g;
        if (a >= N1 && used_g[a - N1]) continue;   // invalid: no effective pairs
        float bx[4] = {sball[a * 4], sball[a * 4 + 1], sball[a * 4 + 2], sball[a * 4 + 3]};
        int lab = (a < N1) ? yl[a] : fl[a - N1];
        u64 ka = make_key(sall[a], a);
        int blo = clampb((int)((bx[0] - wm) * NBSCALE));
        int bhi = clampb((int)(bx[2] * NBSCALE));
        int t0 = roff[lab * NBX + blo];
        int t1 = roff[lab * NBX + bhi + 1];
        for (int t = t0 + tid; t < t1; t += 256) {
            int b = rlst[t];
            if (b > a && !(b >= N1 && used_g[b - N1])) {
                float bb[4] = {sball[b * 4], sball[b * 4 + 1], sball[b * 4 + 2], sball[b * 4 + 3]};
                if (iou_f(bx, bb) >= NMS_IOU_T) {
                    u64 kb = make_key(sall[b], b);
                    int pos = atomicAdd(pcount, 1);
                    if (pos < CAP) {
                        if (ka < kb) { phi[pos] = ka; plo[pos] = kb; }
                        else         { phi[pos] = kb; plo[pos] = ka; }
                    }
                }
            }
        }
    }
}

// kW: single block, 1024 threads. 128-bit bitonic sort of pairs by (hi,lo)
// == (rank_a, rank_b) ascending == exact reference walk order; serial
// suppression over unsorted ids; keep mask written by rank via ord.
__global__ void __launch_bounds__(STH) kW(const int* pcount, const u64* phi,
                                          const u64* plo, const unsigned char* used_g,
                                          const int* ord, float* out) {
    __shared__ u64 hi[CAP];            // 32 KB
    __shared__ u64 lo[CAP];            // 32 KB
    __shared__ unsigned char sup[NT];  //  6 KB
    int tid = threadIdx.x;
    int np = *pcount;
    if (np > CAP) np = CAP;
    int m = 2;
    while (m < np) m <<= 1;   // block-uniform
    for (int t = tid; t < m; t += STH) {
        hi[t] = (t < np) ? phi[t] : ~0ULL;
        lo[t] = (t < np) ? plo[t] : ~0ULL;
    }
    for (int k = tid; k < NT; k += STH)
        sup[k] = (k >= N1 && used_g[k - N1]) ? 1 : 0;
    __syncthreads();
    if (np > 0) {
        for (int k2v = 2; k2v <= m; k2v <<= 1) {
            for (int jj = k2v >> 1; jj > 0; jj >>= 1) {
                for (int idx = tid; idx < m; idx += STH) {
                    int l = idx ^ jj;
                    if (l > idx) {
                        u64 Ah = hi[idx], Al = lo[idx];
                        u64 Bh = hi[l],   Bl = lo[l];
                        bool up = ((idx & k2v) == 0);
                        bool agtb = (Ah > Bh) || (Ah == Bh && Al > Bl);
                        bool altb = (Ah < Bh) || (Ah == Bh && Al < Bl);
                        if (up ? agtb : altb) {
                            hi[idx] = Bh; lo[idx] = Bl;
                            hi[l] = Ah; lo[l] = Al;
                        }
                    }
                }
                __syncthreads();
            }
        }
        if (tid == 0) {
            for (int p = 0; p < np; p++) {
                int ia = (int)(u32)hi[p];
                int ib = (int)(u32)lo[p];
                if (!sup[ia]) sup[ib] = 1;
            }
        }
        __syncthreads();
    }
    for (int r = tid; r < NT; r += STH)
        out[24576 + 2 * NT + r] = sup[ord[r]] ? 0.0f : 1.0f;
}

extern "C" void kernel_launch(void* const* d_in, const int* in_sizes, int n_in,
                              void* d_out, int out_size, void* d_ws, size_t ws_size,
                              hipStream_t stream) {
    const float* yb = (const float*)d_in[0];
    const float* ys = (const float*)d_in[1];
    const int*   yl = (const int*)d_in[2];
    const float* fb = (const float*)d_in[3];
    const float* fs = (const float*)d_in[4];
    const int*   fl = (const int*)d_in[5];
    float* out = (float*)d_out;
    char* ws = (char*)d_ws;

    float*         sball = (float*)(ws);            // 98304 B
    float*         sall  = (float*)(ws + 98304);    // 24576 -> 122880
    int*           ord   = (int*)  (ws + 122880);   // 24576 -> 147456
    unsigned char* usedg = (unsigned char*)(ws + 147456); // 2048 -> 149504
    int*           cnt   = (int*)  (ws + 149504);   // 8 -> 149512
    float*         wmaxf = (float*)(ws + 149512);   // 4 -> 149516
    float*         wmaxa = (float*)(ws + 149516);   // 4 -> 149520
    int*           foff  = (int*)  (ws + 149520);   // 33*4=132 -> 149652
    int*           roff  = (int*)  (ws + 149652);   // 132 -> 149784
    u16*           flst  = (u16*)  (ws + 149784);   // 4096 -> 153880
    u16*           rlst  = (u16*)  (ws + 153880);   // 12288 -> 166168
    u64*           mpk   = (u64*)  (ws + 166168);   // 32768 -> 198936
    float*         mpi   = (float*)(ws + 198936);   // 16384 -> 215320
    u64*           phi   = (u64*)  (ws + 215320);   // 32768 -> 248088
    u64*           plo   = (u64*)  (ws + 248088);   // 32768 -> 280856 (~274 KB)
    int* pcount  = cnt + 0;
    int* mpcount = cnt + 1;

    hipLaunchKernelGGL(k0,  dim3(1),        dim3(STH), 0, stream,
                       fl, fb, cnt, flst, foff, wmaxf);
    hipLaunchKernelGGL(kX,  dim3(N1 + 8),   dim3(256), 0, stream,
                       yb, ys, yl, fb, fs, flst, foff, wmaxf,
                       mpcount, mpk, mpi, sball, sall);
    hipLaunchKernelGGL(k2,  dim3(1),        dim3(STH), 0, stream,
                       fb, fs, yl, fl, mpcount, mpk, mpi, sball, sall, usedg,
                       rlst, roff, wmaxa);
    hipLaunchKernelGGL(kYZ, dim3(NRANKBLK), dim3(256), 0, stream,
                       sball, sall, usedg, yl, fl, rlst, roff, wmaxa,
                       ord, out, pcount, phi, plo);
    hipLaunchKernelGGL(kW,  dim3(1),        dim3(STH), 0, stream,
                       pcount, phi, plo, usedg, ord, out);
}

// Round 24
// 50.799 us; speedup vs baseline: 1.5813x; 1.5813x over previous
//
#include <hip/hip_runtime.h>

typedef unsigned long long u64;
typedef unsigned int u32;
typedef unsigned short u16;

#define N1 4096
#define N2 2048
#define NT 6144
#define CAP 4096
#define MCAP 4096
#define IMG 1280.0f
#define MATCH_IOU_T 0.8f
#define NMS_IOU_T 0.95f
#define NRANKBLK (NT / 16)
#define STH 1024
#define NBX 16            // x1 bins per label
#define BINW_INV (1.0f/80.0f)   // raw-pixel bin width 80 = 1280/16
#define NBSCALE 16.0f     // normalized x1 * 16 -> bin

// IoU with exact op-order mirroring of the reference (no FMA contraction).
__device__ __forceinline__ float iou_f(const float* a, const float* b) {
    float x1 = fmaxf(a[0], b[0]);
    float y1 = fmaxf(a[1], b[1]);
    float x2 = fminf(a[2], b[2]);
    float y2 = fminf(a[3], b[3]);
    float dx = fmaxf(__fsub_rn(x2, x1), 0.0f);
    float dy = fmaxf(__fsub_rn(y2, y1), 0.0f);
    float inter = __fmul_rn(dx, dy);
    float a1 = __fmul_rn(__fsub_rn(a[2], a[0]), __fsub_rn(a[3], a[1]));
    float a2 = __fmul_rn(__fsub_rn(b[2], b[0]), __fsub_rn(b[3], b[1]));
    float den = __fsub_rn(__fadd_rn(a1, a2), inter);
    return __fdiv_rn(inter, den);
}

__device__ __forceinline__ u64 make_key(float f, int idx) {
    u32 u = __float_as_uint(f);
    u32 asc = (u >> 31) ? ~u : (u | 0x80000000u);
    return (((u64)(~asc)) << 32) | (u32)idx;
}

__device__ __forceinline__ u64 row_key(const float* sall, const unsigned char* used_g,
                                       int idx) {
    float sc = sall[idx];
    int val = (idx < N1) ? 1 : (used_g[idx - N1] ? 0 : 1);
    return make_key(val ? sc : -1.0f, idx);
}

__device__ __forceinline__ int clampb(int b) { return min(max(b, 0), NBX - 1); }

// k0: zero counters; bin frcnn boxes into (label x 16 x1-bin) CSR (raw px);
// compute max frcnn width (conservative window margin). Exclusion by bin
// window only removes pairs with PROVABLY zero x-overlap (IoU=0 < thresh).
// List order within a bin is timing-dependent but membership-only (k2 sorts).
__global__ void __launch_bounds__(STH) k0(const int* fl, const float* fb,
                                          int* cnt, u16* flst, int* foff,
                                          float* wmaxf_g) {
    __shared__ int fc[2 * NBX];
    __shared__ int fo[2 * NBX + 1];
    __shared__ float wmx[STH / 64];
    int tid = threadIdx.x;
    if (tid == 0) { cnt[0] = 0; cnt[1] = 0; }
    if (tid < 2 * NBX) fc[tid] = 0;
    __syncthreads();
    float w = 0.0f;
    for (int j = tid; j < N2; j += STH) {
        float x1 = fb[j * 4], x2 = fb[j * 4 + 2];
        w = fmaxf(w, __fsub_rn(x2, x1));
        atomicAdd(&fc[fl[j] * NBX + clampb((int)(x1 * BINW_INV))], 1);
    }
#pragma unroll
    for (int s = 32; s > 0; s >>= 1) w = fmaxf(w, __shfl_down(w, s, 64));
    if ((tid & 63) == 0) wmx[tid >> 6] = w;
    __syncthreads();
    if (tid == 0) {
        float mw = wmx[0];
        for (int q = 1; q < STH / 64; q++) mw = fmaxf(mw, wmx[q]);
        *wmaxf_g = mw + 1.0f;   // +1px slack: absorbs width-rounding, stays conservative
        int acc = 0;
        for (int b = 0; b < 2 * NBX; b++) { fo[b] = acc; acc += fc[b]; }
        fo[2 * NBX] = acc;
    }
    __syncthreads();
    if (tid < 2 * NBX) fc[tid] = fo[tid];     // reuse as fill cursors
    if (tid < 2 * NBX + 1) foff[tid] = fo[tid];
    __syncthreads();
    for (int j = tid; j < N2; j += STH) {
        float x1 = fb[j * 4];
        int p = atomicAdd(&fc[fl[j] * NBX + clampb((int)(x1 * BINW_INV))], 1);
        flst[p] = (u16)j;
    }
}

// kX: blocks [0,N1): one yolo row — scan only same-label frcnn entries whose
// x1-bin can possibly overlap (contiguous CSR range); emit candidate pairs.
// Blocks [N1,N1+8): frcnn rows' defaults.
__global__ void __launch_bounds__(256) kX(const float* yb, const float* ys,
                                          const int* yl, const float* fb,
                                          const float* fs,
                                          const u16* flst, const int* foff,
                                          const float* wmaxf,
                                          int* mpcount, u64* mpk, float* mpi,
                                          float* sball, float* sall) {
    int tid = threadIdx.x;
    if (blockIdx.x < N1) {
        int i = blockIdx.x;
        float ax1 = yb[i * 4], ax2 = yb[i * 4 + 2];
        float a[4];
#pragma unroll
        for (int c = 0; c < 4; c++) a[c] = __fdiv_rn(yb[i * 4 + c], IMG);
        int lab = yl[i];
        float wm = *wmaxf;
        int blo = clampb((int)((ax1 - wm) * BINW_INV));
        int bhi = clampb((int)(ax2 * BINW_INV));
        int t0 = foff[lab * NBX + blo];
        int t1 = foff[lab * NBX + bhi + 1];
        for (int t = t0 + tid; t < t1; t += 256) {
            int j = flst[t];
            float bb[4];
#pragma unroll
            for (int c = 0; c < 4; c++) bb[c] = __fdiv_rn(fb[j * 4 + c], IMG);
            float v = iou_f(a, bb);
            if (v >= MATCH_IOU_T) {
                int pos = atomicAdd(mpcount, 1);
                if (pos < MCAP) { mpk[pos] = (((u64)(u32)i) << 32) | (u32)j; mpi[pos] = v; }
            }
        }
        if (tid == 0) {
#pragma unroll
            for (int c = 0; c < 4; c++) sball[i * 4 + c] = a[c];
            sall[i] = __fmul_rn(ys[i], 0.5f);
        }
    } else {
        int j = (blockIdx.x - N1) * 256 + tid;   // 0..2047
#pragma unroll
        for (int c = 0; c < 4; c++) sball[(N1 + j) * 4 + c] = __fdiv_rn(fb[j * 4 + c], IMG);
        sall[N1 + j] = __fmul_rn(fs[j], 0.5f);
    }
}

// k2: single block, 1024 threads. Sort pairs (init capped to pow2(np)),
// thread-0 greedy walk, merged-row patches + used[]; then build the
// FINAL-box (label x bin) CSR + max-width for the NMS phase.
__global__ void __launch_bounds__(STH) k2(const float* fb, const float* fs,
                                          const int* yl, const int* fl,
                                          const int* mpcount, const u64* mpk,
                                          const float* mpi,
                                          float* sball, float* sall,
                                          unsigned char* used_g,
                                          u16* rlst, int* roff, float* wmaxa_g) {
    __shared__ u64 pk[MCAP];            // 32 KB
    __shared__ float pv[MCAP];          // 16 KB
    __shared__ unsigned char dec[MCAP]; //  4 KB
    __shared__ unsigned char used[N2];  //  2 KB
    __shared__ int rc2[2 * NBX];
    __shared__ int ro[2 * NBX + 1];
    __shared__ float wmx[STH / 64];
    int tid = threadIdx.x;
    int np = *mpcount;
    if (np > MCAP) np = MCAP;
    int m = 2;
    while (m < np) m <<= 1;   // uniform
    for (int t = tid; t < m; t += STH) {
        pk[t] = (t < np) ? mpk[t] : ~0ULL;
        pv[t] = (t < np) ? mpi[t] : 0.0f;
    }
    for (int t = tid; t < np; t += STH) dec[t] = 0;
    for (int j = tid; j < N2; j += STH) used[j] = 0;
    __syncthreads();
    if (np > 0) {
        for (int k2v = 2; k2v <= m; k2v <<= 1) {
            for (int jj = k2v >> 1; jj > 0; jj >>= 1) {
                for (int idx = tid; idx < m; idx += STH) {
                    int l = idx ^ jj;
                    if (l > idx) {
                        u64 A = pk[idx], B = pk[l];
                        bool up = ((idx & k2v) == 0);
                        if (up ? (A > B) : (A < B)) {
                            pk[idx] = B; pk[l] = A;
                            float fA = pv[idx]; pv[idx] = pv[l]; pv[l] = fA;
                        }
                    }
                }
                __syncthreads();
            }
        }
        if (tid == 0) {
            int cur_i = -1, best_p = -1, best_j = -1;
            float best_v = -1.0f;
            for (int p = 0; p < np; p++) {
                u64 pr = pk[p];
                int i = (int)(pr >> 32);
                int j = (int)(pr & 0xffffffffu);
                if (i != cur_i) {
                    if (best_p >= 0) { dec[best_p] = 1; used[best_j] = 1; }
                    cur_i = i; best_p = -1; best_j = -1; best_v = -1.0f;
                }
                if (!used[j]) {
                    float v = pv[p];
                    if (v > best_v) { best_v = v; best_p = p; best_j = j; }
                }
            }
            if (best_p >= 0) { dec[best_p] = 1; used[best_j] = 1; }
        }
        __syncthreads();
        for (int p = tid; p < np; p += STH) {
            if (dec[p]) {
                u64 pr = pk[p];
                int i = (int)(pr >> 32);
                int j = (int)(pr & 0xffffffffu);
                float s2 = __fmul_rn(fs[j], 0.5f);
                float sc0 = sall[i];
                float tot = __fadd_rn(sc0, s2);
#pragma unroll
                for (int cc = 0; cc < 4; cc++) {
                    float b2v = __fdiv_rn(fb[j * 4 + cc], IMG);
                    float merged = __fdiv_rn(
                        __fadd_rn(__fmul_rn(sball[i * 4 + cc], sc0),
                                  __fmul_rn(b2v, s2)), tot);
                    sball[i * 4 + cc] = merged;
                }
                sall[i] = tot;
            }
        }
    }
    for (int j = tid; j < N2; j += STH) used_g[j] = used[j];
    __syncthreads();   // merges + used visible block-wide (intra-block global)
    // ---- final-box bin CSR (normalized x1) + max final width ----
    if (tid < 2 * NBX) rc2[tid] = 0;
    __syncthreads();
    float w = 0.0f;
    for (int r = tid; r < NT; r += STH) {
        float x1 = sball[r * 4], x2 = sball[r * 4 + 2];
        w = fmaxf(w, __fsub_rn(x2, x1));
        int lab = (r < N1) ? yl[r] : fl[r - N1];
        atomicAdd(&rc2[lab * NBX + clampb((int)(x1 * NBSCALE))], 1);
    }
#pragma unroll
    for (int s = 32; s > 0; s >>= 1) w = fmaxf(w, __shfl_down(w, s, 64));
    if ((tid & 63) == 0) wmx[tid >> 6] = w;
    __syncthreads();
    if (tid == 0) {
        float mw = wmx[0];
        for (int q = 1; q < STH / 64; q++) mw = fmaxf(mw, wmx[q]);
        *wmaxa_g = mw + 0.00078125f;   // +1px (normalized) conservative slack
        int acc = 0;
        for (int b = 0; b < 2 * NBX; b++) { ro[b] = acc; acc += rc2[b]; }
        ro[2 * NBX] = acc;
    }
    __syncthreads();
    if (tid < 2 * NBX) rc2[tid] = ro[tid];
    if (tid < 2 * NBX + 1) roff[tid] = ro[tid];
    __syncthreads();
    for (int r = tid; r < NT; r += STH) {
        float x1 = sball[r * 4];
        int lab = (r < N1) ? yl[r] : fl[r - N1];
        int p = atomicAdd(&rc2[lab * NBX + clampb((int)(x1 * NBSCALE))], 1);
        rlst[p] = (u16)r;
    }
}

// kYZ: one grid, two independent roles, no big LDS (r23 lesson: keep the
// NMS role on its own WIDE 6144-block grid — the block count IS the latency
// hiding for its scattered loads; fusing into 384 blocks serialized it).
// blocks [0,384): rank 16 rows against all 6144 inline keys; gather to out.
// blocks [384,384+NT): NMS pairs for row a over its label's bin window
//   (contiguous CSR range; b>a, both valid, IoU >= 0.95).
__global__ void __launch_bounds__(256) kYZ(const float* sball, const float* sall,
                                           const unsigned char* used_g,
                                           const int* yl, const int* fl,
                                           const u16* rlst, const int* roff,
                                           const float* wmaxa,
                                           int* ord, float* out,
                                           int* pcount, u64* phi, u64* plo) {
    __shared__ int cnts[16];
    int tid = threadIdx.x;
    if (blockIdx.x < NRANKBLK) {
        if (tid < 16) cnts[tid] = 0;
        __syncthreads();
        int i0 = blockIdx.x * 16;
        u64 myk[16];
#pragma unroll
        for (int g = 0; g < 16; g++) myk[g] = row_key(sall, used_g, i0 + g);
        int local[16];
#pragma unroll
        for (int g = 0; g < 16; g++) local[g] = 0;
        for (int j = tid; j < NT; j += 256) {
            u64 kj = row_key(sall, used_g, j);
#pragma unroll
            for (int g = 0; g < 16; g++) local[g] += (kj < myk[g]) ? 1 : 0;
        }
#pragma unroll
        for (int g = 0; g < 16; g++) {
            int v = local[g];
#pragma unroll
            for (int s = 32; s > 0; s >>= 1) v += __shfl_down(v, s, 64);
            if ((tid & 63) == 0) atomicAdd(&cnts[g], v);
        }
        __syncthreads();
        if (tid < 16) {
            int i = i0 + tid;
            int r = cnts[tid];
            int lab = (i < N1) ? yl[i] : fl[i - N1];
#pragma unroll
            for (int c = 0; c < 4; c++)
                out[r * 4 + c] = __fmul_rn(sball[i * 4 + c], IMG);
            out[24576 + r] = (lab == 0) ? 2.0f : 1.0f;
            out[24576 + NT + r] = sall[i];
            ord[r] = i;
        }
    } else {
        int a = blockIdx.x - NRANKBLK;
        if (a >= N1 && used_g[a - N1]) return;
        float bx[4] = {sball[a * 4], sball[a * 4 + 1], sball[a * 4 + 2], sball[a * 4 + 3]};
        int lab = (a < N1) ? yl[a] : fl[a - N1];
        u64 ka = make_key(sall[a], a);
        float wm = *wmaxa;
        int blo = clampb((int)((bx[0] - wm) * NBSCALE));
        int bhi = clampb((int)(bx[2] * NBSCALE));
        int t0 = roff[lab * NBX + blo];
        int t1 = roff[lab * NBX + bhi + 1];
        for (int t = t0 + tid; t < t1; t += 256) {
            int b = rlst[t];
            if (b > a && !(b >= N1 && used_g[b - N1])) {
                float bb[4] = {sball[b * 4], sball[b * 4 + 1], sball[b * 4 + 2], sball[b * 4 + 3]};
                if (iou_f(bx, bb) >= NMS_IOU_T) {
                    u64 kb = make_key(sall[b], b);
                    int pos = atomicAdd(pcount, 1);
                    if (pos < CAP) {
                        if (ka < kb) { phi[pos] = ka; plo[pos] = kb; }
                        else         { phi[pos] = kb; plo[pos] = ka; }
                    }
                }
            }
        }
    }
}

// kW: single block, 1024 threads. 128-bit bitonic sort of pairs by (hi,lo)
// == (rank_a, rank_b) ascending == exact reference walk order; serial
// suppression over unsorted ids; keep mask written by rank via ord.
__global__ void __launch_bounds__(STH) kW(const int* pcount, const u64* phi,
                                          const u64* plo, const unsigned char* used_g,
                                          const int* ord, float* out) {
    __shared__ u64 hi[CAP];            // 32 KB
    __shared__ u64 lo[CAP];            // 32 KB
    __shared__ unsigned char sup[NT];  //  6 KB
    int tid = threadIdx.x;
    int np = *pcount;
    if (np > CAP) np = CAP;
    int m = 2;
    while (m < np) m <<= 1;   // block-uniform
    for (int t = tid; t < m; t += STH) {
        hi[t] = (t < np) ? phi[t] : ~0ULL;
        lo[t] = (t < np) ? plo[t] : ~0ULL;
    }
    for (int k = tid; k < NT; k += STH)
        sup[k] = (k >= N1 && used_g[k - N1]) ? 1 : 0;
    __syncthreads();
    if (np > 0) {
        for (int k2v = 2; k2v <= m; k2v <<= 1) {
            for (int jj = k2v >> 1; jj > 0; jj >>= 1) {
                for (int idx = tid; idx < m; idx += STH) {
                    int l = idx ^ jj;
                    if (l > idx) {
                        u64 Ah = hi[idx], Al = lo[idx];
                        u64 Bh = hi[l],   Bl = lo[l];
                        bool up = ((idx & k2v) == 0);
                        bool agtb = (Ah > Bh) || (Ah == Bh && Al > Bl);
                        bool altb = (Ah < Bh) || (Ah == Bh && Al < Bl);
                        if (up ? agtb : altb) {
                            hi[idx] = Bh; lo[idx] = Bl;
                            hi[l] = Ah; lo[l] = Al;
                        }
                    }
                }
                __syncthreads();
            }
        }
        if (tid == 0) {
            for (int p = 0; p < np; p++) {
                int ia = (int)(u32)hi[p];
                int ib = (int)(u32)lo[p];
                if (!sup[ia]) sup[ib] = 1;
            }
        }
        __syncthreads();
    }
    for (int r = tid; r < NT; r += STH)
        out[24576 + 2 * NT + r] = sup[ord[r]] ? 0.0f : 1.0f;
}

extern "C" void kernel_launch(void* const* d_in, const int* in_sizes, int n_in,
                              void* d_out, int out_size, void* d_ws, size_t ws_size,
                              hipStream_t stream) {
    const float* yb = (const float*)d_in[0];
    const float* ys = (const float*)d_in[1];
    const int*   yl = (const int*)d_in[2];
    const float* fb = (const float*)d_in[3];
    const float* fs = (const float*)d_in[4];
    const int*   fl = (const int*)d_in[5];
    float* out = (float*)d_out;
    char* ws = (char*)d_ws;

    float*         sball = (float*)(ws);            // 98304 B
    float*         sall  = (float*)(ws + 98304);    // 24576 -> 122880
    int*           ord   = (int*)  (ws + 122880);   // 24576 -> 147456
    unsigned char* usedg = (unsigned char*)(ws + 147456); // 2048 -> 149504
    int*           cnt   = (int*)  (ws + 149504);   // 8 -> 149512
    float*         wmaxf = (float*)(ws + 149512);   // 4 -> 149516
    float*         wmaxa = (float*)(ws + 149516);   // 4 -> 149520
    int*           foff  = (int*)  (ws + 149520);   // 33*4=132 -> 149652
    int*           roff  = (int*)  (ws + 149652);   // 132 -> 149784
    u16*           flst  = (u16*)  (ws + 149784);   // 4096 -> 153880
    u16*           rlst  = (u16*)  (ws + 153880);   // 12288 -> 166168
    u64*           mpk   = (u64*)  (ws + 166168);   // 32768 -> 198936
    float*         mpi   = (float*)(ws + 198936);   // 16384 -> 215320
    u64*           phi   = (u64*)  (ws + 215320);   // 32768 -> 248088
    u64*           plo   = (u64*)  (ws + 248088);   // 32768 -> 280856 (~274 KB)
    int* pcount  = cnt + 0;
    int* mpcount = cnt + 1;

    hipLaunchKernelGGL(k0,  dim3(1),             dim3(STH), 0, stream,
                       fl, fb, cnt, flst, foff, wmaxf);
    hipLaunchKernelGGL(kX,  dim3(N1 + 8),        dim3(256), 0, stream,
                       yb, ys, yl, fb, fs, flst, foff, wmaxf,
                       mpcount, mpk, mpi, sball, sall);
    hipLaunchKernelGGL(k2,  dim3(1),             dim3(STH), 0, stream,
                       fb, fs, yl, fl, mpcount, mpk, mpi, sball, sall, usedg,
                       rlst, roff, wmaxa);
    hipLaunchKernelGGL(kYZ, dim3(NRANKBLK + NT), dim3(256), 0, stream,
                       sball, sall, usedg, yl, fl, rlst, roff, wmaxa,
                       ord, out, pcount, phi, plo);
    hipLaunchKernelGGL(kW,  dim3(1),             dim3(STH), 0, stream,
                       pcount, phi, plo, usedg, ord, out);
}